// Round 9
// baseline (4927.142 us; speedup 1.0000x reference)
//
#include <hip/hip_runtime.h>
#include <hip/hip_bf16.h>
#include <hip/hip_fp8.h>

#define B 64
#define T 8192
#define D 16
#define H 128
#define F 17        // D + 1 features
#define NTH 1024    // 2 groups x 8 waves
#define CHUNK 32
#define XSTR 40     // xs row stride in halfs
#define GSTRH 528   // gi row stride in halfs (1056 B)

typedef _Float16 half_t;
typedef _Float16 f16x8 __attribute__((ext_vector_type(8)));
typedef _Float16 f16x4 __attribute__((ext_vector_type(4)));
typedef float f32x4 __attribute__((ext_vector_type(4)));
typedef int i32x8 __attribute__((ext_vector_type(8)));

#define MFMA(a, b, c) __builtin_amdgcn_mfma_f32_16x16x32_f16((a), (b), (c), 0, 0, 0)
// fp8(e4m3) x fp8(e4m3), K=128, scales = 1.0 in every E8M0 byte
#define MFMAS(a, b, c) \
  __builtin_amdgcn_mfma_scale_f32_16x16x128_f8f6f4((a), (b), (c), 0, 0, 0, 0x7F7F7F7F, 0, 0x7F7F7F7F)

__device__ __forceinline__ float fast_rcp(float x) {
#if __has_builtin(__builtin_amdgcn_rcpf)
  return __builtin_amdgcn_rcpf(x);
#else
  return 1.0f / x;
#endif
}
__device__ __forceinline__ float fast_exp2(float x) {
#if __has_builtin(__builtin_amdgcn_exp2f)
  return __builtin_amdgcn_exp2f(x);
#else
  return exp2f(x);
#endif
}
__device__ __forceinline__ unsigned char f32_to_e4m3(float f) {
  __hip_fp8_e4m3 q(f);
  return __builtin_bit_cast(unsigned char, q);
}

__global__ __launch_bounds__(NTH, 1)
void policy_gru_kernel(const float* __restrict__ particles,
                       const float* __restrict__ weights,
                       const float* __restrict__ Wi, const float* __restrict__ Wh,
                       const float* __restrict__ bh,
                       const float* __restrict__ W1, const float* __restrict__ b1,
                       const float* __restrict__ W2, const float* __restrict__ b2,
                       const float* __restrict__ W3, const float* __restrict__ b3,
                       const float* __restrict__ log_std,
                       float* __restrict__ out)
{
  // Per-group (2 groups = 2 batches per block) LDS:
  __shared__ __align__(16) unsigned char hb8[2][H];          // h (fp8), single buffer
  __shared__ __align__(16) half_t xs[2][CHUNK * XSTR];       // staged X chunk
  __shared__ __align__(16) half_t gi_lds[2][CHUNK * GSTRH];  // gi[tau][j*4+{r,z,n,p}]
  __shared__ float red[2][8];

  const int tid  = threadIdx.x;
  const int grp  = tid >> 9;       // 0 / 1 : waves 0-7 / 8-15
  const int gtid = tid & 511;
  const int b    = blockIdx.x * 2 + grp;
  const int l    = tid & 63;
  const int w    = gtid >> 6;      // wave within group, 0..7
  const int mg   = l >> 4;         // k-group 0..3 (32 k each)
  const int jn   = l & 15;
  const int jj   = w * 16 + jn;    // hidden unit owned by this lane

  unsigned char* hbp = hb8[grp];
  half_t* xsp = xs[grp];
  half_t* gip = gi_lds[grp];

  const float L1 = 1.4426950408889634f;   // log2(e)
  const float L2 = 2.0f * L1;

  // ---- fp8 Wh B-fragments: gate col jj, k = mg*32 + r*4 + byte (prescaled) ----
  auto wload8 = [&](int gate) -> i32x8 {
    const float sc  = (gate == 2) ? L2 : L1;
    const int   col = gate * H + jj;
    i32x8 v;
    #pragma unroll
    for (int r = 0; r < 8; ++r) {
      unsigned int word = 0;
      #pragma unroll
      for (int byt = 0; byt < 4; ++byt) {
        const int k = mg * 32 + r * 4 + byt;
        word |= ((unsigned int)f32_to_e4m3(Wh[k * 384 + col] * sc)) << (8 * byt);
      }
      v[r] = (int)word;
    }
    return v;
  };
  const i32x8 wb_r = wload8(0), wb_z = wload8(1), wb_n = wload8(2);
  const float bn2 = bh[256 + jj] * L2;

  // ---- f16 Wi B-fragments for the chunk gi matmul, K padded 17->32 ----
  auto wiload = [&](int gate) -> f16x8 {
    f16x8 v;
    const float sc  = (gate == 2) ? L2 : L1;
    const int   col = gate * H + jj;
    #pragma unroll
    for (int i = 0; i < 8; ++i) {
      const int k = mg * 8 + i;
      v[i] = (half_t)(k < F ? Wi[k * 384 + col] * sc : 0.0f);
    }
    return v;
  };
  const f16x8 wiR = wiload(0), wiZ = wiload(1), wiN = wiload(2);
  const float br = bh[jj] * L1, bz = bh[128 + jj] * L1;

  // ---- X chunk prefetch: 544 elements over 512 group-threads (<=2 each) ----
  const int e0 = gtid, e1 = gtid + 512;
  float xr0 = 0.f, xr1 = 0.f;
  auto xfetch = [&](int t0) {
    auto ld = [&](int e) -> float {
      const int tau = e / F, f = e % F;
      int t = t0 + tau; if (t > T - 1) t = T - 1;
      return (f < D) ? particles[((size_t)b * T + t) * D + f]
                     : weights[(size_t)b * T + t];
    };
    xr0 = ld(e0);
    if (e1 < CHUNK * F) xr1 = ld(e1);
  };
  auto xstage = [&]() {
    xsp[(e0 / F) * XSTR + (e0 % F)] = (half_t)xr0;
    if (e1 < CHUNK * F) xsp[(e1 / F) * XSTR + (e1 % F)] = (half_t)xr1;
  };

  // ---- chunk gi matmul: X[32x17] @ Wi -> gi (f16x4/col) — 6 f16-MFMA/wave ----
  // Each wave writes only its own 16 columns; the step-loop gv reads of those
  // columns come from the same wave => same-wave DS program order, no barrier
  // needed between gi_compute and the first gv read of the chunk.
  auto gi_compute = [&]() {
    f16x8 aX0 = *(const f16x8*)(xsp + (jn     ) * XSTR + mg * 8);
    f16x8 aX1 = *(const f16x8*)(xsp + (jn + 16) * XSTR + mg * 8);
    f32x4 cr0 = {br, br, br, br}, cz0 = {bz, bz, bz, bz}, cn0 = {0.f,0.f,0.f,0.f};
    f32x4 cr1 = cr0, cz1 = cz0, cn1 = cn0;
    cr0 = MFMA(aX0, wiR, cr0); cz0 = MFMA(aX0, wiZ, cz0); cn0 = MFMA(aX0, wiN, cn0);
    cr1 = MFMA(aX1, wiR, cr1); cz1 = MFMA(aX1, wiZ, cz1); cn1 = MFMA(aX1, wiN, cn1);
    #pragma unroll
    for (int r = 0; r < 4; ++r) {
      const int t0r = mg * 4 + r;            // D row = timestep within chunk
      *(f16x4*)(gip + t0r * GSTRH + jj * 4) =
          f16x4{(half_t)cr0[r], (half_t)cz0[r], (half_t)cn0[r], (half_t)0.f};
      const int t1r = t0r + 16;
      *(f16x4*)(gip + t1r * GSTRH + jj * 4) =
          f16x4{(half_t)cr1[r], (half_t)cz1[r], (half_t)cn1[r], (half_t)0.f};
    }
  };

  // ---- persistent per-step state (lives across barriers) ----
  const f32x4 zc = {0.f, 0.f, 0.f, 0.f};
  f32x4 ar = zc, az = zc, an = zc;
  f16x4 gv = {};
  float hreg = 0.0f;

  // MFMA interval for step t: issue matvec, prefetch gv; results used next interval
  auto mfma_phase = [&](int t) {
    if ((t & 31) == 0 && t > 0) gi_compute();
    const i32x8 a8 = *(const i32x8*)(hbp + mg * 32);
    ar = MFMAS(a8, wb_r, zc);
    az = MFMAS(a8, wb_z, zc);
    an = MFMAS(a8, wb_n, zc);
    gv = *(const f16x4*)(gip + (t & 31) * GSTRH + jj * 4);
  };

  // Gates interval for step t: consume MFMA results, update h, write hb
  auto gates_phase = [&](int t) {
    float sr = ar[0] + (float)gv[0];
    float sz = az[0] + (float)gv[1];
    float rr = fast_rcp(1.0f + fast_exp2(-sr));
    float zz = fast_rcp(1.0f + fast_exp2(-sz));
    float pre = fmaf(rr, an[0] + bn2, (float)gv[2]);
    pre = fmaxf(pre, -120.0f);
    float e = fast_exp2(-pre);
    float nn = (1.0f - e) * fast_rcp(1.0f + e);
    hreg = fmaf(zz, hreg - nn, nn);  /* (1-z)*n + z*h */
    if (mg == 0) hbp[jj] = f32_to_e4m3(hreg);
    if ((t & 31) == 31) { xstage(); xfetch(t + 1 + CHUNK); }
  };

  // ---- prologue: zero h/xs, stage chunk 0, compute gi chunk 0 ----
  if (gtid < H) hbp[gtid] = 0;                    // fp8 zero
  for (int i = gtid; i < CHUNK * XSTR; i += 512) xsp[i] = (half_t)0.f;
  xfetch(0);
  __syncthreads();
  xstage();
  xfetch(CHUNK);
  __syncthreads();
  gi_compute();
  __syncthreads();

  // ---- phase-interleaved scan: group 0 leads, group 1 trails by one interval ----
  for (int t = 0; t < T; ++t) {
    if (grp == 0) mfma_phase(t); else if (t > 0) gates_phase(t - 1);
    __syncthreads();
    if (grp == 0) gates_phase(t); else mfma_phase(t);
    __syncthreads();
  }
  if (grp == 1) gates_phase(T - 1);
  __syncthreads();

  // ---- MLP head (fp32), per group, scratch aliases gi region ----
  float* sg = (float*)gi_lds[grp];
  if (mg == 0) sg[jj] = hreg;   // final hidden state
  __syncthreads();

  float a1 = 0.0f;
  if (gtid < 256) {
    a1 = b1[gtid];
    #pragma unroll 4
    for (int k = 0; k < H; ++k) a1 = fmaf(sg[k], W1[k * 256 + gtid], a1);
    a1 = fmaxf(a1, 0.0f);
    sg[256 + gtid] = a1;   // disjoint from sg[0..127]
  }
  __syncthreads();

  float a2 = 0.0f;
  if (gtid < 256) {
    a2 = b2[gtid];
    #pragma unroll 4
    for (int k = 0; k < 256; ++k) a2 = fmaf(sg[256 + k], W2[k * 256 + gtid], a2);
    a2 = fmaxf(a2, 0.0f);
    a2 *= W3[gtid];        // W3 is [256,1]
  }
  #pragma unroll
  for (int off = 32; off > 0; off >>= 1) a2 += __shfl_down(a2, off, 64);
  if (gtid < 256 && (gtid & 63) == 0) red[grp][gtid >> 6] = a2;
  __syncthreads();
  if (gtid == 0) {
    out[b] = red[grp][0] + red[grp][1] + red[grp][2] + red[grp][3] + b3[0];
    if (b == 0) out[B] = log_std[0];  // second output, flat index 64
  }
}

extern "C" void kernel_launch(void* const* d_in, const int* in_sizes, int n_in,
                              void* d_out, int out_size, void* d_ws, size_t ws_size,
                              hipStream_t stream) {
  const float* particles = (const float*)d_in[0];
  const float* weights   = (const float*)d_in[1];
  const float* Wi      = (const float*)d_in[2];
  const float* Wh      = (const float*)d_in[3];
  const float* bh      = (const float*)d_in[4];
  const float* W1      = (const float*)d_in[5];
  const float* b1      = (const float*)d_in[6];
  const float* W2      = (const float*)d_in[7];
  const float* b2      = (const float*)d_in[8];
  const float* W3      = (const float*)d_in[9];
  const float* b3      = (const float*)d_in[10];
  const float* log_std = (const float*)d_in[11];

  policy_gru_kernel<<<dim3(B / 2), dim3(NTH), 0, stream>>>(
      particles, weights, Wi, Wh, bh, W1, b1, W2, b2, W3, b3, log_std,
      (float*)d_out);
}